// Round 6
// baseline (548.517 us; speedup 1.0000x reference)
//
#include <hip/hip_runtime.h>
#include <cstdint>
#include <cstddef>

#define B_     256
#define D_     2048
#define U_     2048
#define NTOT   8192    // 4*U
#define KS     8       // k-splits (4 over W, 4 over U)
#define KSLICE 512     // K per split
#define KSTEPS (KSLICE / 16)   // 32 MFMA k-steps per wave

typedef _Float16 half8 __attribute__((ext_vector_type(8)));
typedef _Float16 half4 __attribute__((ext_vector_type(4)));
typedef float floatx16 __attribute__((ext_vector_type(16)));

// ---------------------------------------------------------------------------
// prep: [x|h] fp32 -> f16, k-octet-major [koct = k/8][row][8]: GEMM reads
// MFMA A-fragments directly from this buffer as aligned 16B loads.
// ---------------------------------------------------------------------------
__global__ __launch_bounds__(256) void prep_kernel(
    const float* __restrict__ x, const float* __restrict__ h,
    _Float16* __restrict__ Ahi)
{
    int gid   = blockIdx.x * 256 + threadIdx.x;   // 131072 total
    int koct  = gid >> 8;                         // 0..511
    int row   = gid & 255;
    int col0  = koct * 8;
    const float* src = (col0 < D_) ? (x + row * D_ + col0)
                                   : (h + row * U_ + (col0 - D_));
    float4 v0 = *(const float4*)(src);
    float4 v1 = *(const float4*)(src + 4);
    float v[8] = {v0.x, v0.y, v0.z, v0.w, v1.x, v1.y, v1.z, v1.w};
    half8 hi;
#pragma unroll
    for (int i = 0; i < 8; ++i) hi[i] = (_Float16)v[i];
    *(half8*)(Ahi + (koct * 256 + row) * 8) = hi;
}

// ---------------------------------------------------------------------------
// GEMM, barrier-free per-wave streaming.  Each wave owns (n-strip of 32,
// k-slice of 512): 8 m-tiles of 32x32x16 covering all M=256 rows, so every
// weight element is read by exactly one wave.  No LDS, no __syncthreads =>
// no vmcnt drains ever; 2-deep register double-buffer keeps a full k-step
// of loads in flight across the MFMA block, and 8 waves/CU (2/SIMD) keep
// the VMEM queue populated continuously.
// B-fragment loads: lane reads W[k0+j][c0+lm] -> 2x128B segments/instr.
// A-fragment loads: 16B/lane from koct-major f16 buffer (L2-resident).
// Partials stored f16 (halves P traffic; error ~1e-3 pre-act, harmless).
// ---------------------------------------------------------------------------
__global__ __launch_bounds__(256, 2) void gemm_kernel(
    const _Float16* __restrict__ Ahi,
    const float* __restrict__ Wz, const float* __restrict__ Wi,
    const float* __restrict__ Wf, const float* __restrict__ Wo,
    const float* __restrict__ Uz, const float* __restrict__ Ui,
    const float* __restrict__ Uf, const float* __restrict__ Uo,
    _Float16* __restrict__ P)
{
    const int t    = threadIdx.x;
    const int w    = t >> 6;
    const int lane = t & 63;
    const int lg   = lane >> 5;
    const int lm   = lane & 31;

    const int wid   = blockIdx.x * 4 + w;   // 0..2047
    const int strip = wid & 255;            // n-strip
    const int ks    = wid >> 8;             // 0..7
    const int n0    = strip * 32;
    const int g     = n0 >> 11;             // gate
    const int c0    = n0 & (U_ - 1);
    const int krow0 = (ks & 3) * KSLICE;    // k base inside weight matrix
    const int koctB = ks * (KSLICE / 8);    // A k-octet base (ks*64)

    const float* wsel[8] = {Wz, Wi, Wf, Wo, Uz, Ui, Uf, Uo};
    const float* Bm = wsel[(ks >> 2) * 4 + g];
    const float* Bbase = Bm + (size_t)krow0 * U_ + c0 + lm;  // lane's column

    floatx16 acc[8] = {};

    float breg[2][8];
    half8 areg[2][8];

#define LOADK(kk, buf)                                                        \
    {                                                                         \
        const float* bp = Bbase + (size_t)((kk) * 16 + lg * 8) * U_;          \
        _Pragma("unroll")                                                     \
        for (int j = 0; j < 8; ++j) breg[buf][j] = bp[(size_t)j * U_];        \
        const _Float16* ap =                                                  \
            Ahi + ((size_t)(koctB + (kk) * 2 + lg) * 256 + lm) * 8;           \
        _Pragma("unroll")                                                     \
        for (int mt = 0; mt < 8; ++mt)                                        \
            areg[buf][mt] = *(const half8*)(ap + mt * 32 * 8);                \
    }

    LOADK(0, 0);

    for (int kk = 0; kk < KSTEPS; ++kk) {
        int cur = kk & 1;
        if (kk + 1 < KSTEPS) LOADK(kk + 1, cur ^ 1);
        half8 b;
#pragma unroll
        for (int j = 0; j < 8; ++j) b[j] = (_Float16)breg[cur][j];
#pragma unroll
        for (int mt = 0; mt < 8; ++mt)
            acc[mt] = __builtin_amdgcn_mfma_f32_32x32x16_f16(
                areg[cur][mt], b, acc[mt], 0, 0, 0);
    }
#undef LOADK

    // C/D layout: col=lane&31, row=(r&3)+8*(r>>2)+4*(lane>>5)
    _Float16* Pks = P + (size_t)ks * ((size_t)B_ * NTOT);
#pragma unroll
    for (int mt = 0; mt < 8; ++mt)
#pragma unroll
        for (int r = 0; r < 16; ++r) {
            int m = mt * 32 + 4 * lg + (r & 3) + 8 * (r >> 2);
            Pks[(size_t)m * NTOT + n0 + lm] = (_Float16)acc[mt][r];
        }
}

// ---------------------------------------------------------------------------
// gates: reduce 8 f16 partials, add bias, sLSTM exponential-gate math,
// out = stack([h_t, c_t, n_t, m_t])
// ---------------------------------------------------------------------------
__global__ __launch_bounds__(256) void gates_kernel(
    const _Float16* __restrict__ P,
    const float* __restrict__ c_prev, const float* __restrict__ n_prev,
    const float* __restrict__ m_prev,
    const float* __restrict__ bz, const float* __restrict__ bi,
    const float* __restrict__ bf, const float* __restrict__ bo,
    float* __restrict__ out)
{
    const size_t PS = (size_t)B_ * NTOT;
    const int OS = B_ * U_;
    int gid = blockIdx.x * 256 + threadIdx.x;   // 131072
    int m = gid >> 9;
    int u = (gid & 511) * 4;

    float pre[4][4];
#pragma unroll
    for (int gi = 0; gi < 4; ++gi) {
        const _Float16* base = P + (size_t)m * NTOT + gi * U_ + u;
        float s[4] = {0.f, 0.f, 0.f, 0.f};
#pragma unroll
        for (int sp = 0; sp < KS; ++sp) {
            half4 v = *(const half4*)(base + sp * PS);
            s[0] += (float)v[0]; s[1] += (float)v[1];
            s[2] += (float)v[2]; s[3] += (float)v[3];
        }
        pre[gi][0] = s[0]; pre[gi][1] = s[1];
        pre[gi][2] = s[2]; pre[gi][3] = s[3];
    }
    float4 bzv = *(const float4*)(bz + u);
    float4 biv = *(const float4*)(bi + u);
    float4 bfv = *(const float4*)(bf + u);
    float4 bov = *(const float4*)(bo + u);
    float bza[4] = {bzv.x, bzv.y, bzv.z, bzv.w};
    float bia[4] = {biv.x, biv.y, biv.z, biv.w};
    float bfa[4] = {bfv.x, bfv.y, bfv.z, bfv.w};
    float boa[4] = {bov.x, bov.y, bov.z, bov.w};

    float4 cp4 = *(const float4*)(c_prev + m * U_ + u);
    float4 np4 = *(const float4*)(n_prev + m * U_ + u);
    float4 mp4 = *(const float4*)(m_prev + m * U_ + u);
    float cpa[4] = {cp4.x, cp4.y, cp4.z, cp4.w};
    float npa[4] = {np4.x, np4.y, np4.z, np4.w};
    float mpa[4] = {mp4.x, mp4.y, mp4.z, mp4.w};

    float hr[4], cr[4], nr[4], mr[4];
#pragma unroll
    for (int e = 0; e < 4; ++e) {
        float zt = pre[0][e] + bza[e];
        float it = pre[1][e] + bia[e];
        float ft = pre[2][e] + bfa[e];
        float ot = pre[3][e] + boa[e];
        float mp = mpa[e];
        float m_t = fmaxf(it + mp, it);
        float i_t = expf(it - m_t);
        float f_t = expf(ft + mp - m_t);
        float o_t = 1.0f / (1.0f + expf(-ot));
        float z_t = tanhf(zt);
        float c_t = f_t * cpa[e] + i_t * z_t;
        float n_t = f_t * npa[e] + i_t;
        float h_t = o_t * (c_t / (n_t + 1e-8f));
        hr[e] = h_t; cr[e] = c_t; nr[e] = n_t; mr[e] = m_t;
    }
    float4 hv = {hr[0], hr[1], hr[2], hr[3]};
    float4 cv = {cr[0], cr[1], cr[2], cr[3]};
    float4 nv = {nr[0], nr[1], nr[2], nr[3]};
    float4 mv = {mr[0], mr[1], mr[2], mr[3]};
    *(float4*)(out + 0 * OS + m * U_ + u) = hv;
    *(float4*)(out + 1 * OS + m * U_ + u) = cv;
    *(float4*)(out + 2 * OS + m * U_ + u) = nv;
    *(float4*)(out + 3 * OS + m * U_ + u) = mv;
}

extern "C" void kernel_launch(void* const* d_in, const int* in_sizes, int n_in,
                              void* d_out, int out_size, void* d_ws, size_t ws_size,
                              hipStream_t stream)
{
    const float* x  = (const float*)d_in[0];
    const float* h  = (const float*)d_in[1];
    const float* cp = (const float*)d_in[2];
    const float* np = (const float*)d_in[3];
    const float* mp = (const float*)d_in[4];
    const float* Wz = (const float*)d_in[5];
    const float* Wi = (const float*)d_in[6];
    const float* Wf = (const float*)d_in[7];
    const float* Wo = (const float*)d_in[8];
    const float* bz = (const float*)d_in[9];
    const float* bi = (const float*)d_in[10];
    const float* bf = (const float*)d_in[11];
    const float* bo = (const float*)d_in[12];
    const float* Uz = (const float*)d_in[13];
    const float* Ui = (const float*)d_in[14];
    const float* Uf = (const float*)d_in[15];
    const float* Uo = (const float*)d_in[16];

    _Float16* P = (_Float16*)d_ws;   // 8*256*8192 f16 = 33.55 MB
    _Float16* Ahi = (_Float16*)((char*)d_ws + (size_t)KS * B_ * NTOT * sizeof(_Float16));

    prep_kernel<<<512, 256, 0, stream>>>(x, h, Ahi);
    gemm_kernel<<<512, 256, 0, stream>>>(Ahi,
        Wz, Wi, Wf, Wo, Uz, Ui, Uf, Uo, P);
    gates_kernel<<<512, 256, 0, stream>>>(P, cp, np, mp, bz, bi, bf, bo,
        (float*)d_out);
}

// Round 7
// 224.620 us; speedup vs baseline: 2.4420x; 2.4420x over previous
//
#include <hip/hip_runtime.h>
#include <cstdint>
#include <cstddef>

#define B_     256
#define D_     2048
#define U_     2048
#define NTOT   8192    // 4*U
#define KS     8       // k-splits (4 over W, 4 over U)
#define KSLICE 512     // K per split
#define KSTEPS (KSLICE / 16)   // 32 MFMA k-steps per wave

typedef _Float16 half8 __attribute__((ext_vector_type(8)));
typedef _Float16 half4 __attribute__((ext_vector_type(4)));
typedef float floatx16 __attribute__((ext_vector_type(16)));

// ---------------------------------------------------------------------------
// prep: [x|h] fp32 -> f16, k-octet-major [koct = k/8][row][8]: GEMM reads
// MFMA A-fragments directly from this buffer as aligned 16B loads.
// ---------------------------------------------------------------------------
__global__ __launch_bounds__(256) void prep_kernel(
    const float* __restrict__ x, const float* __restrict__ h,
    _Float16* __restrict__ Ahi)
{
    int gid   = blockIdx.x * 256 + threadIdx.x;   // 131072 total
    int koct  = gid >> 8;                         // 0..511
    int row   = gid & 255;
    int col0  = koct * 8;
    const float* src = (col0 < D_) ? (x + row * D_ + col0)
                                   : (h + row * U_ + (col0 - D_));
    float4 v0 = *(const float4*)(src);
    float4 v1 = *(const float4*)(src + 4);
    float v[8] = {v0.x, v0.y, v0.z, v0.w, v1.x, v1.y, v1.z, v1.w};
    half8 hi;
#pragma unroll
    for (int i = 0; i < 8; ++i) hi[i] = (_Float16)v[i];
    *(half8*)(Ahi + (koct * 256 + row) * 8) = hi;
}

// ---------------------------------------------------------------------------
// GEMM, barrier-free per-wave streaming.  Each wave owns (n-strip of 32,
// k-slice of 512): 8 m-tiles of 32x32x16 covering all M=256 rows, so every
// weight element is read by exactly one wave.  No LDS, no __syncthreads =>
// no vmcnt drains; manual unroll-by-2 register double buffer with DISTINCT
// NAMED VARIABLE SETS (compile-time indices only — runtime-indexed arrays
// get demoted to scratch, which was round 6's 565 MB WRITE_SIZE bug).
// B-fragment loads: 64 lanes x 4B = 2x128B segments/instr straight from the
// fp32 weights.  A-fragment loads: 16B/lane from the prepped f16 buffer
// (2 MB, L2-resident).  Partials stored f16.
// ---------------------------------------------------------------------------
__global__ __launch_bounds__(256, 2) void gemm_kernel(
    const _Float16* __restrict__ Ahi,
    const float* __restrict__ Wz, const float* __restrict__ Wi,
    const float* __restrict__ Wf, const float* __restrict__ Wo,
    const float* __restrict__ Uz, const float* __restrict__ Ui,
    const float* __restrict__ Uf, const float* __restrict__ Uo,
    _Float16* __restrict__ P)
{
    const int t    = threadIdx.x;
    const int w    = t >> 6;
    const int lane = t & 63;
    const int lg   = lane >> 5;
    const int lm   = lane & 31;

    const int wid   = blockIdx.x * 4 + w;   // 0..2047
    const int strip = wid & 255;            // n-strip
    const int ks    = wid >> 8;             // 0..7
    const int n0    = strip * 32;
    const int g     = n0 >> 11;             // gate
    const int c0    = n0 & (U_ - 1);
    const int krow0 = (ks & 3) * KSLICE;    // k base inside weight matrix
    const int koctB = ks * (KSLICE / 8);    // A k-octet base (ks*64)

    const float* wsel[8] = {Wz, Wi, Wf, Wo, Uz, Ui, Uf, Uo};
    const float* Bm = wsel[(ks >> 2) * 4 + g];
    const float* Bbase = Bm + (size_t)krow0 * U_ + c0 + lm;  // lane's column
    const _Float16* Abase = Ahi + ((size_t)(koctB + lg) * 256 + lm) * 8;

    floatx16 acc[8] = {};

    float breg0[8], breg1[8];
    half8 areg0[8], areg1[8];

#define LOADK(kk, BR, AR)                                                     \
    {                                                                         \
        const float* bp = Bbase + (size_t)((kk) * 16 + lg * 8) * U_;          \
        _Pragma("unroll")                                                     \
        for (int j = 0; j < 8; ++j) BR[j] = bp[(size_t)j * U_];               \
        const _Float16* ap = Abase + (size_t)(kk) * 2 * 256 * 8;              \
        _Pragma("unroll")                                                     \
        for (int mt = 0; mt < 8; ++mt)                                        \
            AR[mt] = *(const half8*)(ap + mt * 32 * 8);                       \
    }

#define COMPUTE(BR, AR)                                                       \
    {                                                                         \
        half8 b;                                                              \
        _Pragma("unroll")                                                     \
        for (int j = 0; j < 8; ++j) b[j] = (_Float16)BR[j];                   \
        _Pragma("unroll")                                                     \
        for (int mt = 0; mt < 8; ++mt)                                        \
            acc[mt] = __builtin_amdgcn_mfma_f32_32x32x16_f16(                 \
                AR[mt], b, acc[mt], 0, 0, 0);                                 \
    }

    LOADK(0, breg0, areg0);

#pragma unroll 1
    for (int kk = 0; kk < KSTEPS; kk += 2) {
        LOADK(kk + 1, breg1, areg1);
        COMPUTE(breg0, areg0);
        if (kk + 2 < KSTEPS) LOADK(kk + 2, breg0, areg0);
        COMPUTE(breg1, areg1);
    }
#undef LOADK
#undef COMPUTE

    // C/D layout: col=lane&31, row=(r&3)+8*(r>>2)+4*(lane>>5)
    _Float16* Pks = P + (size_t)ks * ((size_t)B_ * NTOT);
#pragma unroll
    for (int mt = 0; mt < 8; ++mt)
#pragma unroll
        for (int r = 0; r < 16; ++r) {
            int m = mt * 32 + 4 * lg + (r & 3) + 8 * (r >> 2);
            Pks[(size_t)m * NTOT + n0 + lm] = (_Float16)acc[mt][r];
        }
}

// ---------------------------------------------------------------------------
// gates: reduce 8 f16 partials, add bias, sLSTM exponential-gate math,
// out = stack([h_t, c_t, n_t, m_t])
// ---------------------------------------------------------------------------
__global__ __launch_bounds__(256) void gates_kernel(
    const _Float16* __restrict__ P,
    const float* __restrict__ c_prev, const float* __restrict__ n_prev,
    const float* __restrict__ m_prev,
    const float* __restrict__ bz, const float* __restrict__ bi,
    const float* __restrict__ bf, const float* __restrict__ bo,
    float* __restrict__ out)
{
    const size_t PS = (size_t)B_ * NTOT;
    const int OS = B_ * U_;
    int gid = blockIdx.x * 256 + threadIdx.x;   // 131072
    int m = gid >> 9;
    int u = (gid & 511) * 4;

    float pre[4][4];
#pragma unroll
    for (int gi = 0; gi < 4; ++gi) {
        const _Float16* base = P + (size_t)m * NTOT + gi * U_ + u;
        float s[4] = {0.f, 0.f, 0.f, 0.f};
#pragma unroll
        for (int sp = 0; sp < KS; ++sp) {
            half4 v = *(const half4*)(base + sp * PS);
            s[0] += (float)v[0]; s[1] += (float)v[1];
            s[2] += (float)v[2]; s[3] += (float)v[3];
        }
        pre[gi][0] = s[0]; pre[gi][1] = s[1];
        pre[gi][2] = s[2]; pre[gi][3] = s[3];
    }
    float4 bzv = *(const float4*)(bz + u);
    float4 biv = *(const float4*)(bi + u);
    float4 bfv = *(const float4*)(bf + u);
    float4 bov = *(const float4*)(bo + u);
    float bza[4] = {bzv.x, bzv.y, bzv.z, bzv.w};
    float bia[4] = {biv.x, biv.y, biv.z, biv.w};
    float bfa[4] = {bfv.x, bfv.y, bfv.z, bfv.w};
    float boa[4] = {bov.x, bov.y, bov.z, bov.w};

    float4 cp4 = *(const float4*)(c_prev + m * U_ + u);
    float4 np4 = *(const float4*)(n_prev + m * U_ + u);
    float4 mp4 = *(const float4*)(m_prev + m * U_ + u);
    float cpa[4] = {cp4.x, cp4.y, cp4.z, cp4.w};
    float npa[4] = {np4.x, np4.y, np4.z, np4.w};
    float mpa[4] = {mp4.x, mp4.y, mp4.z, mp4.w};

    float hr[4], cr[4], nr[4], mr[4];
#pragma unroll
    for (int e = 0; e < 4; ++e) {
        float zt = pre[0][e] + bza[e];
        float it = pre[1][e] + bia[e];
        float ft = pre[2][e] + bfa[e];
        float ot = pre[3][e] + boa[e];
        float mp = mpa[e];
        float m_t = fmaxf(it + mp, it);
        float i_t = expf(it - m_t);
        float f_t = expf(ft + mp - m_t);
        float o_t = 1.0f / (1.0f + expf(-ot));
        float z_t = tanhf(zt);
        float c_t = f_t * cpa[e] + i_t * z_t;
        float n_t = f_t * npa[e] + i_t;
        float h_t = o_t * (c_t / (n_t + 1e-8f));
        hr[e] = h_t; cr[e] = c_t; nr[e] = n_t; mr[e] = m_t;
    }
    float4 hv = {hr[0], hr[1], hr[2], hr[3]};
    float4 cv = {cr[0], cr[1], cr[2], cr[3]};
    float4 nv = {nr[0], nr[1], nr[2], nr[3]};
    float4 mv = {mr[0], mr[1], mr[2], mr[3]};
    *(float4*)(out + 0 * OS + m * U_ + u) = hv;
    *(float4*)(out + 1 * OS + m * U_ + u) = cv;
    *(float4*)(out + 2 * OS + m * U_ + u) = nv;
    *(float4*)(out + 3 * OS + m * U_ + u) = mv;
}

extern "C" void kernel_launch(void* const* d_in, const int* in_sizes, int n_in,
                              void* d_out, int out_size, void* d_ws, size_t ws_size,
                              hipStream_t stream)
{
    const float* x  = (const float*)d_in[0];
    const float* h  = (const float*)d_in[1];
    const float* cp = (const float*)d_in[2];
    const float* np = (const float*)d_in[3];
    const float* mp = (const float*)d_in[4];
    const float* Wz = (const float*)d_in[5];
    const float* Wi = (const float*)d_in[6];
    const float* Wf = (const float*)d_in[7];
    const float* Wo = (const float*)d_in[8];
    const float* bz = (const float*)d_in[9];
    const float* bi = (const float*)d_in[10];
    const float* bf = (const float*)d_in[11];
    const float* bo = (const float*)d_in[12];
    const float* Uz = (const float*)d_in[13];
    const float* Ui = (const float*)d_in[14];
    const float* Uf = (const float*)d_in[15];
    const float* Uo = (const float*)d_in[16];

    _Float16* P = (_Float16*)d_ws;   // 8*256*8192 f16 = 33.55 MB
    _Float16* Ahi = (_Float16*)((char*)d_ws + (size_t)KS * B_ * NTOT * sizeof(_Float16));

    prep_kernel<<<512, 256, 0, stream>>>(x, h, Ahi);
    gemm_kernel<<<512, 256, 0, stream>>>(Ahi,
        Wz, Wi, Wf, Wo, Uz, Ui, Uf, Uo, P);
    gates_kernel<<<512, 256, 0, stream>>>(P, cp, np, mp, bz, bi, bf, bo,
        (float*)d_out);
}